// Round 5
// baseline (406.671 us; speedup 1.0000x reference)
//
#include <hip/hip_runtime.h>
#include <math.h>

#define D 128
#define BSH 6
#define BMASK 63
#define NT 64          // targets per bucket
#define NB 1563        // ceil(100000/64)
#define CAP 2432       // per-bucket capacity (mean 2048, +8.5 sigma)
#define EPB 8192       // edges per k_bin block (16 per thread, 512 threads)
#define LDA 136        // LDS row stride (bf16 units): 2-way bank aliasing = free

typedef unsigned short ushort_t;
typedef unsigned int uint_t;
typedef __attribute__((ext_vector_type(8))) short bfrag;   // 8 bf16 = 4 VGPRs
typedef __attribute__((ext_vector_type(4))) float ffrag;   // 4 fp32 acc

__device__ inline ushort_t f2bf(float f) {
    uint_t u = __float_as_uint(f);
    uint_t r = (u + 0x7FFFu + ((u >> 16) & 1u)) >> 16;
    return (ushort_t)r;
}

// ---------------- binning + degree count (+ fused W^T bf16 conversion in blocks 0..15) ----------------
__global__ __launch_bounds__(512) void k_bin(const int* __restrict__ src,
                                             const int* __restrict__ tgt, int e,
                                             int* __restrict__ bucket_cur,
                                             uint_t* __restrict__ binned,
                                             int* __restrict__ deg,
                                             const float* __restrict__ W,
                                             ushort_t* __restrict__ Wt) {
    __shared__ int lcnt[NB];      // 6.3 KB
    __shared__ int lbase[NB];     // 6.3 KB
    int tid = threadIdx.x;

    // fused Wt[n][k] = bf16(W[k][n]) — 16 blocks x 1024 elems (first 256 threads)
    if (blockIdx.x < 16 && tid < 256) {
        int nrow = blockIdx.x * 8 + (tid >> 5);
        int k0 = (tid & 31) * 4;
        ushort4 o;
        o.x = f2bf(W[(size_t)(k0 + 0) * D + nrow]);
        o.y = f2bf(W[(size_t)(k0 + 1) * D + nrow]);
        o.z = f2bf(W[(size_t)(k0 + 2) * D + nrow]);
        o.w = f2bf(W[(size_t)(k0 + 3) * D + nrow]);
        *(ushort4*)&Wt[(size_t)nrow * D + k0] = o;
    }

    int base = blockIdx.x * EPB;
    for (int i = tid; i < NB; i += 512) lcnt[i] = 0;
    __syncthreads();

    int myb[16], myrank[16];
    uint_t myval[16];
#pragma unroll
    for (int k = 0; k < 16; ++k) {
        int i = base + k * 512 + tid;
        if (i < e) {
            int t = tgt[i];
            int s = src[i];
            int b = t >> BSH;
            myb[k] = b;
            myval[k] = ((uint_t)s << BSH) | (uint_t)(t & BMASK);
            myrank[k] = atomicAdd(&lcnt[b], 1);
            atomicAdd(&deg[t], 1);               // global degree for k_gemm's dinv
        } else {
            myb[k] = -1;
        }
    }
    __syncthreads();
    for (int i = tid; i < NB; i += 512) {
        int c = lcnt[i];
        lbase[i] = (c > 0) ? atomicAdd(&bucket_cur[i], c) : 0;
    }
    __syncthreads();
#pragma unroll
    for (int k = 0; k < 16; ++k) {
        if (myb[k] >= 0) {
            int slot = lbase[myb[k]] + myrank[k];
            if (slot < CAP) binned[(size_t)myb[k] * CAP + slot] = myval[k];
        }
    }
}

// ---------------- Y = dinv*(X@W) bf16 via MFMA (transposed-operand trick), xnorm fused ----------------
__global__ __launch_bounds__(256) void k_gemm(const float* __restrict__ X,
                                              const ushort_t* __restrict__ Wt,
                                              const int* __restrict__ deg,
                                              ushort_t* __restrict__ Y,
                                              float* __restrict__ xnorm, int n) {
    __shared__ ushort_t As[64 * LDA];    // X tile, bf16
    __shared__ ushort_t Bs[128 * LDA];   // Wt (n x k), bf16
    int tid = threadIdx.x;
    int row0 = blockIdx.x * 64;

    for (int i = tid; i < 128 * 16; i += 256) {
        int nr = i >> 4, c = (i & 15) << 3;
        *(uint4*)&Bs[nr * LDA + c] = *(const uint4*)&Wt[(size_t)nr * D + c];
    }

    const float4* X4 = (const float4*)X;
#pragma unroll
    for (int i2 = 0; i2 < 8; ++i2) {
        int item = i2 * 256 + tid;
        int r = item >> 5, c4 = item & 31;
        int gr = row0 + r;
        float4 v = (gr < n) ? X4[(size_t)gr * 32 + c4] : make_float4(0.f, 0.f, 0.f, 0.f);
        ushort4 bv;
        bv.x = f2bf(v.x); bv.y = f2bf(v.y); bv.z = f2bf(v.z); bv.w = f2bf(v.w);
        *(ushort4*)&As[r * LDA + c4 * 4] = bv;
        float s = v.x * v.x + v.y * v.y + v.z * v.z + v.w * v.w;
        s += __shfl_xor(s, 1);
        s += __shfl_xor(s, 2);
        s += __shfl_xor(s, 4);
        s += __shfl_xor(s, 8);
        s += __shfl_xor(s, 16);
        if ((tid & 31) == 0 && gr < n) xnorm[gr] = sqrtf(s);
    }
    __syncthreads();

    int w = tid >> 6;
    int lane = tid & 63;
    int q = lane >> 4;
    int mi = lane & 15;

    bfrag xf[4];
#pragma unroll
    for (int kt = 0; kt < 4; ++kt)
        xf[kt] = *(const bfrag*)&As[(w * 16 + mi) * LDA + kt * 32 + q * 8];

    ffrag acc[8];
#pragma unroll
    for (int nt = 0; nt < 8; ++nt) acc[nt] = (ffrag){0.f, 0.f, 0.f, 0.f};

#pragma unroll
    for (int nt = 0; nt < 8; ++nt) {
#pragma unroll
        for (int kt = 0; kt < 4; ++kt) {
            bfrag wf = *(const bfrag*)&Bs[(nt * 16 + mi) * LDA + kt * 32 + q * 8];
            acc[nt] = __builtin_amdgcn_mfma_f32_16x16x32_bf16(wf, xf[kt], acc[nt], 0, 0, 0);
        }
    }

    int gr = row0 + w * 16 + mi;
    if (gr < n) {
        float dv = rsqrtf((float)deg[gr] + 1.0f);   // dinv inline from degree (+1 self loop)
#pragma unroll
        for (int nt = 0; nt < 8; ++nt) {
            ushort4 o;
            o.x = f2bf(acc[nt][0] * dv);
            o.y = f2bf(acc[nt][1] * dv);
            o.z = f2bf(acc[nt][2] * dv);
            o.w = f2bf(acc[nt][3] * dv);
            *(ushort4*)&Y[(size_t)gr * D + nt * 16 + q * 4] = o;
        }
    }
}

// ---------------- fused LDS counting-sort + aggregation + MessageNorm + GELU ----------------
// Block = one bucket of 64 targets. Prologue sorts the bucket's edges by target in LDS
// (replaces the entire k_sort kernel and the col/rowptr HBM round-trips). Then 4 waves x
// 16 targets each run the register-resident gather with wave-uniform scalar addressing.
// dinv[t] comes from the in-block histogram for free.
__global__ __launch_bounds__(256) void k_agg(const ushort_t* __restrict__ Y,
                                             const float* __restrict__ xnorm,
                                             const uint_t* __restrict__ binned,
                                             const int* __restrict__ bucket_cur,
                                             const float* __restrict__ bias,
                                             const float* __restrict__ scale,
                                             float* __restrict__ out, int n) {
    __shared__ uint_t ssrc[CAP];     // 9.5 KB sorted source indices
    __shared__ int scnt[NT];
    __shared__ int sbeg[NT];
    __shared__ int sofs[NT];
    int b = blockIdx.x;
    int tid = threadIdx.x;
    int wv = tid >> 6;
    int lane = tid & 63;

    int nb = min(bucket_cur[b], CAP);
    const uint_t* bin = binned + (size_t)b * CAP;

    // histogram of local targets
    if (tid < NT) scnt[tid] = 0;
    __syncthreads();
    for (int i = tid; i < nb; i += 256)
        atomicAdd(&scnt[bin[i] & BMASK], 1);
    __syncthreads();
    // exclusive scan over 64 counters: wave 0, shfl-based
    if (tid < 64) {
        int c = scnt[tid];
        int x = c;
#pragma unroll
        for (int off = 1; off < 64; off <<= 1) {
            int y = __shfl_up(x, off);
            if (lane >= off) x += y;
        }
        sbeg[tid] = x - c;
        sofs[tid] = x - c;
    }
    __syncthreads();
    // scatter: sorted-by-target source list in LDS
    for (int i = tid; i < nb; i += 256) {
        uint_t w = bin[i];
        int r = atomicAdd(&sofs[w & BMASK], 1);
        ssrc[r] = w >> BSH;
    }
    __syncthreads();

    const char* Yb = (const char*)Y;
    uint_t lo4 = (uint_t)lane * 4;
    float b0 = bias[lane * 2];
    float b1 = bias[lane * 2 + 1];
    float sc = scale[0];

    for (int i = 0; i < 16; ++i) {
        int tl = wv * 16 + i;
        int t = (b << BSH) + tl;
        if (t >= n) break;
        int cnt = scnt[tl];
        int beg = sbeg[tl];

        uint_t p = *(const uint_t*)(Yb + (((uint_t)t << 8) + lo4));   // self loop
        float a0 = __uint_as_float(p << 16);
        float a1 = __uint_as_float(p & 0xFFFF0000u);

        for (int base = 0; base < cnt; base += 64) {
            int m = min(cnt - base, 64);
            uint_t cv = ssrc[beg + base + min(lane, m - 1)];   // LDS, conflict-free
            int k = 0;
            for (; k + 16 <= m; k += 16) {
                uint_t qv[16];
#pragma unroll
                for (int j = 0; j < 16; ++j) {
                    uint_t s = (uint_t)__builtin_amdgcn_readlane((int)cv, k + j);
                    qv[j] = *(const uint_t*)(Yb + ((size_t)s << 8) + lo4);
                }
#pragma unroll
                for (int j = 0; j < 16; ++j) {
                    a0 += __uint_as_float(qv[j] << 16);
                    a1 += __uint_as_float(qv[j] & 0xFFFF0000u);
                }
            }
            for (; k + 4 <= m; k += 4) {
                uint_t qv[4];
#pragma unroll
                for (int j = 0; j < 4; ++j) {
                    uint_t s = (uint_t)__builtin_amdgcn_readlane((int)cv, k + j);
                    qv[j] = *(const uint_t*)(Yb + ((size_t)s << 8) + lo4);
                }
#pragma unroll
                for (int j = 0; j < 4; ++j) {
                    a0 += __uint_as_float(qv[j] << 16);
                    a1 += __uint_as_float(qv[j] & 0xFFFF0000u);
                }
            }
            for (; k < m; ++k) {
                uint_t s = (uint_t)__builtin_amdgcn_readlane((int)cv, k);
                uint_t q = *(const uint_t*)(Yb + ((size_t)s << 8) + lo4);
                a0 += __uint_as_float(q << 16);
                a1 += __uint_as_float(q & 0xFFFF0000u);
            }
        }

        float dt = rsqrtf((float)cnt + 1.0f);
        float m0 = fmaf(dt, a0, b0);
        float m1 = fmaf(dt, a1, b1);

        float m2 = m0 * m0 + m1 * m1;
#pragma unroll
        for (int mm = 32; mm >= 1; mm >>= 1) m2 += __shfl_xor(m2, mm);

        float denom = fmaxf(sqrtf(m2), 1e-12f);
        float fac = xnorm[t] * sc / denom;
        float g0 = m0 * fac;
        float g1 = m1 * fac;
        float2 o;
        o.x = 0.5f * g0 * (1.0f + erff(g0 * 0.70710678118654752440f));
        o.y = 0.5f * g1 * (1.0f + erff(g1 * 0.70710678118654752440f));
        *(float2*)&out[(size_t)t * D + lane * 2] = o;
    }
}

// ---------------- launch ----------------

extern "C" void kernel_launch(void* const* d_in, const int* in_sizes, int n_in,
                              void* d_out, int out_size, void* d_ws, size_t ws_size,
                              hipStream_t stream) {
    const float* X     = (const float*)d_in[0];
    const int*   ei    = (const int*)d_in[1];
    const float* W     = (const float*)d_in[2];
    const float* bias  = (const float*)d_in[3];
    const float* scale = (const float*)d_in[4];
    float* out = (float*)d_out;

    int n = in_sizes[0] / D;     // 100000
    int e = in_sizes[1] / 2;     // 3200000
    const int* src = ei;
    const int* tgt = ei + e;

    char* ws = (char*)d_ws;
    ushort_t* Y = (ushort_t*)ws;   ws += (size_t)n * D * sizeof(ushort_t);     // 25.6 MB
    uint_t* binned = (uint_t*)ws;  ws += (size_t)NB * CAP * sizeof(uint_t);    // 15.2 MB (live until k_agg)
    float* xnorm = (float*)ws;     ws += (size_t)n * sizeof(float);
    int* deg = (int*)ws;           ws += (size_t)n * sizeof(int);
    int* bucket_cur = (int*)ws;    ws += NB * sizeof(int);
    ushort_t* Wt = (ushort_t*)ws;  /* 32 KB */

    // deg and bucket_cur are adjacent: one memset clears both
    hipMemsetAsync(deg, 0, ((size_t)n + NB) * sizeof(int), stream);
    k_bin<<<(e + EPB - 1) / EPB, 512, 0, stream>>>(src, tgt, e, bucket_cur, binned, deg, W, Wt);
    k_gemm<<<(n + 63) / 64, 256, 0, stream>>>(X, Wt, deg, Y, xnorm, n);
    k_agg<<<NB, 256, 0, stream>>>(Y, xnorm, binned, bucket_cur, bias, scale, out, n);
}

// Round 6
// 325.805 us; speedup vs baseline: 1.2482x; 1.2482x over previous
//
#include <hip/hip_runtime.h>
#include <math.h>

#define D 128
#define BSH 7
#define BMASK 127
#define NT 128         // targets per bucket
#define NB 782         // buckets of 128 targets
#define CAP 4608       // per-bucket capacity (mean 4092, +8 sigma) — validated r1/r3/r4
#define EPB 4096
#define LDA 136        // LDS row stride (bf16 units): 2-way bank aliasing = free

typedef unsigned short ushort_t;
typedef unsigned int uint_t;
typedef __attribute__((ext_vector_type(8))) short bfrag;   // 8 bf16 = 4 VGPRs
typedef __attribute__((ext_vector_type(4))) float ffrag;   // 4 fp32 acc

__device__ inline ushort_t f2bf(float f) {
    uint_t u = __float_as_uint(f);
    uint_t r = (u + 0x7FFFu + ((u >> 16) & 1u)) >> 16;
    return (ushort_t)r;
}

// ---------------- binning (+ fused W^T bf16 conversion in blocks 0..15) ----------------
// NOTE: no per-edge global atomics here — round 5 showed 3.2M device-scope atomicAdds
// to a hot region cost ~150us of pure serialization. Degree comes from k_deg's LDS pass.
__global__ __launch_bounds__(256) void k_bin(const int* __restrict__ src,
                                             const int* __restrict__ tgt, int e,
                                             int* __restrict__ bucket_cur,
                                             uint_t* __restrict__ binned,
                                             const float* __restrict__ W,
                                             ushort_t* __restrict__ Wt) {
    __shared__ int lcnt[NB];
    __shared__ int lbase[NB];
    int tid = threadIdx.x;

    // fused Wt[n][k] = bf16(W[k][n]) — 16 blocks x 1024 elems
    if (blockIdx.x < 16) {
        int nrow = blockIdx.x * 8 + (tid >> 5);
        int k0 = (tid & 31) * 4;
        ushort4 o;
        o.x = f2bf(W[(size_t)(k0 + 0) * D + nrow]);
        o.y = f2bf(W[(size_t)(k0 + 1) * D + nrow]);
        o.z = f2bf(W[(size_t)(k0 + 2) * D + nrow]);
        o.w = f2bf(W[(size_t)(k0 + 3) * D + nrow]);
        *(ushort4*)&Wt[(size_t)nrow * D + k0] = o;
    }

    int base = blockIdx.x * EPB;
    for (int i = tid; i < NB; i += 256) lcnt[i] = 0;
    __syncthreads();

    int myb[16], myrank[16];
    uint_t myval[16];
#pragma unroll
    for (int k = 0; k < 16; ++k) {
        int i = base + k * 256 + tid;
        if (i < e) {
            int t = tgt[i];
            int s = src[i];
            int b = t >> BSH;
            myb[k] = b;
            myval[k] = ((uint_t)s << BSH) | (uint_t)(t & BMASK);
            myrank[k] = atomicAdd(&lcnt[b], 1);
        } else {
            myb[k] = -1;
        }
    }
    __syncthreads();
    for (int i = tid; i < NB; i += 256) {
        int c = lcnt[i];
        lbase[i] = (c > 0) ? atomicAdd(&bucket_cur[i], c) : 0;
    }
    __syncthreads();
#pragma unroll
    for (int k = 0; k < 16; ++k) {
        if (myb[k] >= 0) {
            int slot = lbase[myb[k]] + myrank[k];
            if (slot < CAP) binned[(size_t)myb[k] * CAP + slot] = myval[k];
        }
    }
}

// ---------------- per-bucket degree count -> dinv (LDS histogram; cheap, validated r1) ----------------
__global__ __launch_bounds__(256) void k_deg(const uint_t* __restrict__ binned,
                                             const int* __restrict__ bucket_cur,
                                             float* __restrict__ dinv, int n) {
    __shared__ int scnt[NT];
    int b = blockIdx.x;
    int tid = threadIdx.x;
    if (tid < NT) scnt[tid] = 0;
    __syncthreads();
    int nb = min(bucket_cur[b], CAP);
    const uint_t* bin = binned + (size_t)b * CAP;
    for (int i = tid; i < nb; i += 256)
        atomicAdd(&scnt[bin[i] & BMASK], 1);
    __syncthreads();
    if (tid < NT) {
        int t = (b << BSH) + tid;
        if (t < n) dinv[t] = rsqrtf((float)scnt[tid] + 1.0f);
    }
}

// ---------------- Y = dinv*(X@W) bf16 via MFMA (transposed-operand trick), xnorm fused ----------------
__global__ __launch_bounds__(256) void k_gemm(const float* __restrict__ X,
                                              const ushort_t* __restrict__ Wt,
                                              const float* __restrict__ dinv,
                                              ushort_t* __restrict__ Y,
                                              float* __restrict__ xnorm, int n) {
    __shared__ ushort_t As[64 * LDA];    // X tile, bf16
    __shared__ ushort_t Bs[128 * LDA];   // Wt (n x k), bf16
    int tid = threadIdx.x;
    int row0 = blockIdx.x * 64;

    for (int i = tid; i < 128 * 16; i += 256) {
        int nr = i >> 4, c = (i & 15) << 3;
        *(uint4*)&Bs[nr * LDA + c] = *(const uint4*)&Wt[(size_t)nr * D + c];
    }

    const float4* X4 = (const float4*)X;
#pragma unroll
    for (int i2 = 0; i2 < 8; ++i2) {
        int item = i2 * 256 + tid;
        int r = item >> 5, c4 = item & 31;
        int gr = row0 + r;
        float4 v = (gr < n) ? X4[(size_t)gr * 32 + c4] : make_float4(0.f, 0.f, 0.f, 0.f);
        ushort4 bv;
        bv.x = f2bf(v.x); bv.y = f2bf(v.y); bv.z = f2bf(v.z); bv.w = f2bf(v.w);
        *(ushort4*)&As[r * LDA + c4 * 4] = bv;
        float s = v.x * v.x + v.y * v.y + v.z * v.z + v.w * v.w;
        s += __shfl_xor(s, 1);
        s += __shfl_xor(s, 2);
        s += __shfl_xor(s, 4);
        s += __shfl_xor(s, 8);
        s += __shfl_xor(s, 16);
        if ((tid & 31) == 0 && gr < n) xnorm[gr] = sqrtf(s);
    }
    __syncthreads();

    int w = tid >> 6;
    int lane = tid & 63;
    int q = lane >> 4;
    int mi = lane & 15;

    bfrag xf[4];
#pragma unroll
    for (int kt = 0; kt < 4; ++kt)
        xf[kt] = *(const bfrag*)&As[(w * 16 + mi) * LDA + kt * 32 + q * 8];

    ffrag acc[8];
#pragma unroll
    for (int nt = 0; nt < 8; ++nt) acc[nt] = (ffrag){0.f, 0.f, 0.f, 0.f};

#pragma unroll
    for (int nt = 0; nt < 8; ++nt) {
#pragma unroll
        for (int kt = 0; kt < 4; ++kt) {
            bfrag wf = *(const bfrag*)&Bs[(nt * 16 + mi) * LDA + kt * 32 + q * 8];
            acc[nt] = __builtin_amdgcn_mfma_f32_16x16x32_bf16(wf, xf[kt], acc[nt], 0, 0, 0);
        }
    }

    int gr = row0 + w * 16 + mi;
    if (gr < n) {
        float dv = dinv[gr];
#pragma unroll
        for (int nt = 0; nt < 8; ++nt) {
            ushort4 o;
            o.x = f2bf(acc[nt][0] * dv);
            o.y = f2bf(acc[nt][1] * dv);
            o.z = f2bf(acc[nt][2] * dv);
            o.w = f2bf(acc[nt][3] * dv);
            *(ushort4*)&Y[(size_t)gr * D + nt * 16 + q * 4] = o;
        }
    }
}

// ---------------- fused LDS counting-sort + aggregation + MessageNorm + GELU ----------------
// Block = one bucket of 128 targets (replaces the k_sort kernel and the col/rowptr
// HBM round-trips). LDS: 18KB ssrc + 1.5KB counters -> 8 blocks/CU (full occupancy).
// Gather phase = round-3's validated wave-per-target readlane/scalar-address pattern.
__global__ __launch_bounds__(256) void k_agg(const ushort_t* __restrict__ Y,
                                             const float* __restrict__ xnorm,
                                             const uint_t* __restrict__ binned,
                                             const int* __restrict__ bucket_cur,
                                             const float* __restrict__ bias,
                                             const float* __restrict__ scale,
                                             float* __restrict__ out, int n) {
    __shared__ uint_t ssrc[CAP];     // 18 KB sorted source indices
    __shared__ int scnt[NT];
    __shared__ int sbeg[NT];
    __shared__ int sofs[NT];
    int b = blockIdx.x;
    int tid = threadIdx.x;
    int wv = tid >> 6;
    int lane = tid & 63;

    int nb = min(bucket_cur[b], CAP);
    const uint_t* bin = binned + (size_t)b * CAP;

    // histogram of local targets
    if (tid < NT) scnt[tid] = 0;
    __syncthreads();
    for (int i = tid; i < nb; i += 256)
        atomicAdd(&scnt[bin[i] & BMASK], 1);
    __syncthreads();
    // exclusive scan over 128 counters: wave 0 handles both 64-halves via shfl
    if (tid < 64) {
        int c0 = scnt[lane];
        int c1 = scnt[lane + 64];
        int x0 = c0, x1 = c1;
#pragma unroll
        for (int off = 1; off < 64; off <<= 1) {
            int y0 = __shfl_up(x0, off);
            int y1 = __shfl_up(x1, off);
            if (lane >= off) { x0 += y0; x1 += y1; }
        }
        int tot0 = __shfl(x0, 63);
        x1 += tot0;
        sbeg[lane] = x0 - c0;      sofs[lane] = x0 - c0;
        sbeg[lane + 64] = x1 - c1; sofs[lane + 64] = x1 - c1;
    }
    __syncthreads();
    // scatter: sorted-by-target source list in LDS
    for (int i = tid; i < nb; i += 256) {
        uint_t w = bin[i];
        int r = atomicAdd(&sofs[w & BMASK], 1);
        ssrc[r] = w >> BSH;
    }
    __syncthreads();

    const char* Yb = (const char*)Y;
    uint_t lo4 = (uint_t)lane * 4;
    float b0 = bias[lane * 2];
    float b1 = bias[lane * 2 + 1];
    float sc = scale[0];

    for (int i = 0; i < 32; ++i) {
        int tl = wv * 32 + i;
        int t = (b << BSH) + tl;
        if (t >= n) break;
        int cnt = scnt[tl];
        int beg = sbeg[tl];

        uint_t p = *(const uint_t*)(Yb + (((uint_t)t << 8) + lo4));   // self loop
        float a0 = __uint_as_float(p << 16);
        float a1 = __uint_as_float(p & 0xFFFF0000u);

        for (int base = 0; base < cnt; base += 64) {
            int m = min(cnt - base, 64);
            uint_t cv = ssrc[beg + base + min(lane, m - 1)];   // LDS, conflict-free
            int k = 0;
            for (; k + 16 <= m; k += 16) {
                uint_t qv[16];
#pragma unroll
                for (int j = 0; j < 16; ++j) {
                    uint_t s = (uint_t)__builtin_amdgcn_readlane((int)cv, k + j);
                    qv[j] = *(const uint_t*)(Yb + ((size_t)s << 8) + lo4);
                }
#pragma unroll
                for (int j = 0; j < 16; ++j) {
                    a0 += __uint_as_float(qv[j] << 16);
                    a1 += __uint_as_float(qv[j] & 0xFFFF0000u);
                }
            }
            for (; k + 4 <= m; k += 4) {
                uint_t qv[4];
#pragma unroll
                for (int j = 0; j < 4; ++j) {
                    uint_t s = (uint_t)__builtin_amdgcn_readlane((int)cv, k + j);
                    qv[j] = *(const uint_t*)(Yb + ((size_t)s << 8) + lo4);
                }
#pragma unroll
                for (int j = 0; j < 4; ++j) {
                    a0 += __uint_as_float(qv[j] << 16);
                    a1 += __uint_as_float(qv[j] & 0xFFFF0000u);
                }
            }
            for (; k < m; ++k) {
                uint_t s = (uint_t)__builtin_amdgcn_readlane((int)cv, k);
                uint_t q = *(const uint_t*)(Yb + ((size_t)s << 8) + lo4);
                a0 += __uint_as_float(q << 16);
                a1 += __uint_as_float(q & 0xFFFF0000u);
            }
        }

        float dt = rsqrtf((float)cnt + 1.0f);
        float m0 = fmaf(dt, a0, b0);
        float m1 = fmaf(dt, a1, b1);

        float m2 = m0 * m0 + m1 * m1;
#pragma unroll
        for (int mm = 32; mm >= 1; mm >>= 1) m2 += __shfl_xor(m2, mm);

        float denom = fmaxf(sqrtf(m2), 1e-12f);
        float fac = xnorm[t] * sc / denom;
        float g0 = m0 * fac;
        float g1 = m1 * fac;
        float2 o;
        o.x = 0.5f * g0 * (1.0f + erff(g0 * 0.70710678118654752440f));
        o.y = 0.5f * g1 * (1.0f + erff(g1 * 0.70710678118654752440f));
        *(float2*)&out[(size_t)t * D + lane * 2] = o;
    }
}

// ---------------- launch ----------------

extern "C" void kernel_launch(void* const* d_in, const int* in_sizes, int n_in,
                              void* d_out, int out_size, void* d_ws, size_t ws_size,
                              hipStream_t stream) {
    const float* X     = (const float*)d_in[0];
    const int*   ei    = (const int*)d_in[1];
    const float* W     = (const float*)d_in[2];
    const float* bias  = (const float*)d_in[3];
    const float* scale = (const float*)d_in[4];
    float* out = (float*)d_out;

    int n = in_sizes[0] / D;     // 100000
    int e = in_sizes[1] / 2;     // 3200000
    const int* src = ei;
    const int* tgt = ei + e;

    char* ws = (char*)d_ws;
    ushort_t* Y = (ushort_t*)ws;   ws += (size_t)n * D * sizeof(ushort_t);     // 25.6 MB
    uint_t* binned = (uint_t*)ws;  ws += (size_t)NB * CAP * sizeof(uint_t);    // 14.4 MB (live until k_agg)
    float* dinv = (float*)ws;      ws += (size_t)n * sizeof(float);
    float* xnorm = (float*)ws;     ws += (size_t)n * sizeof(float);
    int* bucket_cur = (int*)ws;    ws += NB * sizeof(int);
    ushort_t* Wt = (ushort_t*)ws;  /* 32 KB */

    hipMemsetAsync(bucket_cur, 0, NB * sizeof(int), stream);
    k_bin<<<(e + EPB - 1) / EPB, 256, 0, stream>>>(src, tgt, e, bucket_cur, binned, W, Wt);
    k_deg<<<NB, 256, 0, stream>>>(binned, bucket_cur, dinv, n);
    k_gemm<<<(n + 63) / 64, 256, 0, stream>>>(X, Wt, dinv, Y, xnorm, n);
    k_agg<<<NB, 256, 0, stream>>>(Y, xnorm, binned, bucket_cur, bias, scale, out, n);
}

// Round 7
// 313.564 us; speedup vs baseline: 1.2969x; 1.0390x over previous
//
#include <hip/hip_runtime.h>
#include <math.h>

#define D 128
#define NB 782         // buckets of 128 targets
#define BSH 7
#define BMASK 127
#define CAP 4608       // per-bucket capacity (mean 4092, +8 sigma) — validated r1/r3/r4
#define EPB 4096
#define LDA 136        // LDS row stride (bf16 units): 2-way bank aliasing = free

typedef unsigned short ushort_t;
typedef unsigned int uint_t;
typedef __attribute__((ext_vector_type(8))) short bfrag;   // 8 bf16 = 4 VGPRs
typedef __attribute__((ext_vector_type(4))) float ffrag;   // 4 fp32 acc

__device__ inline ushort_t f2bf(float f) {
    uint_t u = __float_as_uint(f);
    uint_t r = (u + 0x7FFFu + ((u >> 16) & 1u)) >> 16;
    return (ushort_t)r;
}

// ---------------- binning (+ fused W^T bf16 conversion in blocks 0..15) ----------------
// 1024 threads x 4 edges (was 256 x 16): grid stays 782 blocks but occupancy goes
// 12 -> 32 waves/CU, and the serial {load, LDS-atomic, scatter} chain shrinks 16 -> 4.
__global__ __launch_bounds__(1024) void k_bin(const int* __restrict__ src,
                                              const int* __restrict__ tgt, int e,
                                              int* __restrict__ bucket_cur,
                                              uint_t* __restrict__ binned,
                                              const float* __restrict__ W,
                                              ushort_t* __restrict__ Wt) {
    __shared__ int lcnt[NB];
    __shared__ int lbase[NB];
    int tid = threadIdx.x;

    // fused Wt[n][k] = bf16(W[k][n]) — 16 blocks x 1024 elems (first 256 threads)
    if (blockIdx.x < 16 && tid < 256) {
        int nrow = blockIdx.x * 8 + (tid >> 5);
        int k0 = (tid & 31) * 4;
        ushort4 o;
        o.x = f2bf(W[(size_t)(k0 + 0) * D + nrow]);
        o.y = f2bf(W[(size_t)(k0 + 1) * D + nrow]);
        o.z = f2bf(W[(size_t)(k0 + 2) * D + nrow]);
        o.w = f2bf(W[(size_t)(k0 + 3) * D + nrow]);
        *(ushort4*)&Wt[(size_t)nrow * D + k0] = o;
    }

    int base = blockIdx.x * EPB;
    for (int i = tid; i < NB; i += 1024) lcnt[i] = 0;
    __syncthreads();

    int i0 = base + tid * 4;
    int myb[4], myrank[4];
    uint_t myval[4];
    if (i0 + 3 < e) {
        int4 s4 = *(const int4*)&src[i0];
        int4 t4 = *(const int4*)&tgt[i0];
        int ss[4] = {s4.x, s4.y, s4.z, s4.w};
        int tt[4] = {t4.x, t4.y, t4.z, t4.w};
#pragma unroll
        for (int k = 0; k < 4; ++k) {
            int b = tt[k] >> BSH;
            myb[k] = b;
            myval[k] = ((uint_t)ss[k] << BSH) | (uint_t)(tt[k] & BMASK);
            myrank[k] = atomicAdd(&lcnt[b], 1);
        }
    } else {
#pragma unroll
        for (int k = 0; k < 4; ++k) {
            int i = i0 + k;
            if (i < e) {
                int t = tgt[i];
                int b = t >> BSH;
                myb[k] = b;
                myval[k] = ((uint_t)src[i] << BSH) | (uint_t)(t & BMASK);
                myrank[k] = atomicAdd(&lcnt[b], 1);
            } else {
                myb[k] = -1;
            }
        }
    }
    __syncthreads();
    for (int i = tid; i < NB; i += 1024) {
        int c = lcnt[i];
        lbase[i] = (c > 0) ? atomicAdd(&bucket_cur[i], c) : 0;
    }
    __syncthreads();
#pragma unroll
    for (int k = 0; k < 4; ++k) {
        if (myb[k] >= 0) {
            int slot = lbase[myb[k]] + myrank[k];
            if (slot < CAP) binned[(size_t)myb[k] * CAP + slot] = myval[k];
        }
    }
}

// ---------------- per-bucket LDS counting sort (+ fused bucket-base prefix) ----------------
__global__ __launch_bounds__(256) void k_sort(const uint_t* __restrict__ binned,
                                              const int* __restrict__ bucket_cur,
                                              int* __restrict__ col,
                                              int* __restrict__ rowptr,
                                              float* __restrict__ dinv, int n) {
    __shared__ uint_t sout[CAP];     // 18 KB
    __shared__ int scnt[128];
    __shared__ int sincl[128];
    __shared__ int sofs[128];
    __shared__ int sred[256];
    int b = blockIdx.x;
    int tid = threadIdx.x;

    // bucket base = sum of counts of buckets < b
    int v = 0;
    for (int i = tid; i < b; i += 256) v += min(bucket_cur[i], CAP);
    sred[tid] = v;
    __syncthreads();
    for (int off = 128; off >= 1; off >>= 1) {
        if (tid < off) sred[tid] += sred[tid + off];
        __syncthreads();
    }
    int baseg = sred[0];

    int nb = min(bucket_cur[b], CAP);
    const uint_t* bin = binned + (size_t)b * CAP;

    if (tid < 128) scnt[tid] = 0;
    __syncthreads();
    for (int i = tid; i < nb; i += 256)
        atomicAdd(&scnt[bin[i] & BMASK], 1);
    __syncthreads();
    int x = 0;
    if (tid < 128) {
        x = scnt[tid];
        sincl[tid] = x;
    }
    __syncthreads();
    for (int off = 1; off < 128; off <<= 1) {
        int y = 0;
        if (tid < 128 && tid >= off) y = sincl[tid - off];
        __syncthreads();
        if (tid < 128) {
            x += y;
            sincl[tid] = x;
        }
        __syncthreads();
    }
    if (tid < 128) {
        sofs[tid] = x - scnt[tid];
        int t = (b << BSH) + tid;
        if (t < n) {
            rowptr[t + 1] = baseg + x;
            dinv[t] = rsqrtf((float)scnt[tid] + 1.0f);
        }
    }
    if (b == 0 && tid == 0) rowptr[0] = 0;
    __syncthreads();
    for (int i = tid; i < nb; i += 256) {
        uint_t w = bin[i];
        int r = atomicAdd(&sofs[w & BMASK], 1);
        sout[r] = w >> BSH;
    }
    __syncthreads();
    for (int i = tid; i < nb; i += 256)
        col[baseg + i] = (int)sout[i];
}

// ---------------- Y = dinv*(X@W) bf16 via MFMA (transposed-operand trick), xnorm fused ----------------
// Wt (32 KB, shared by ALL blocks) is read directly from global (L1/L2-hot) instead of
// being staged into LDS: As-only LDS (17.4 KB) lifts occupancy 3 -> 8 blocks/CU.
__global__ __launch_bounds__(256) void k_gemm(const float* __restrict__ X,
                                              const ushort_t* __restrict__ Wt,
                                              const float* __restrict__ dinv,
                                              ushort_t* __restrict__ Y,
                                              float* __restrict__ xnorm, int n) {
    __shared__ ushort_t As[64 * LDA];    // X tile, bf16
    int tid = threadIdx.x;
    int row0 = blockIdx.x * 64;

    const float4* X4 = (const float4*)X;
#pragma unroll
    for (int i2 = 0; i2 < 8; ++i2) {
        int item = i2 * 256 + tid;
        int r = item >> 5, c4 = item & 31;
        int gr = row0 + r;
        float4 v = (gr < n) ? X4[(size_t)gr * 32 + c4] : make_float4(0.f, 0.f, 0.f, 0.f);
        ushort4 bv;
        bv.x = f2bf(v.x); bv.y = f2bf(v.y); bv.z = f2bf(v.z); bv.w = f2bf(v.w);
        *(ushort4*)&As[r * LDA + c4 * 4] = bv;
        float s = v.x * v.x + v.y * v.y + v.z * v.z + v.w * v.w;
        s += __shfl_xor(s, 1);
        s += __shfl_xor(s, 2);
        s += __shfl_xor(s, 4);
        s += __shfl_xor(s, 8);
        s += __shfl_xor(s, 16);
        if ((tid & 31) == 0 && gr < n) xnorm[gr] = sqrtf(s);
    }
    __syncthreads();

    int w = tid >> 6;
    int lane = tid & 63;
    int q = lane >> 4;
    int mi = lane & 15;

    bfrag xf[4];
#pragma unroll
    for (int kt = 0; kt < 4; ++kt)
        xf[kt] = *(const bfrag*)&As[(w * 16 + mi) * LDA + kt * 32 + q * 8];

    ffrag acc[8];
#pragma unroll
    for (int nt = 0; nt < 8; ++nt) acc[nt] = (ffrag){0.f, 0.f, 0.f, 0.f};

#pragma unroll
    for (int nt = 0; nt < 8; ++nt) {
#pragma unroll
        for (int kt = 0; kt < 4; ++kt) {
            bfrag wf = *(const bfrag*)&Wt[(size_t)(nt * 16 + mi) * D + kt * 32 + q * 8];
            acc[nt] = __builtin_amdgcn_mfma_f32_16x16x32_bf16(wf, xf[kt], acc[nt], 0, 0, 0);
        }
    }

    int gr = row0 + w * 16 + mi;
    if (gr < n) {
        float dv = dinv[gr];
#pragma unroll
        for (int nt = 0; nt < 8; ++nt) {
            ushort4 o;
            o.x = f2bf(acc[nt][0] * dv);
            o.y = f2bf(acc[nt][1] * dv);
            o.z = f2bf(acc[nt][2] * dv);
            o.w = f2bf(acc[nt][3] * dv);
            *(ushort4*)&Y[(size_t)gr * D + nt * 16 + q * 4] = o;
        }
    }
}

// ---------------- fused aggregation + MessageNorm + GELU (wave per target) ----------------
// r3-validated version: wave-uniform readlane/scalar addressing, 25000 blocks, 77% occ.
__global__ __launch_bounds__(256) void k_agg(const ushort_t* __restrict__ Y,
                                             const float* __restrict__ xnorm,
                                             const float* __restrict__ dinv,
                                             const int* __restrict__ rowptr,
                                             const int* __restrict__ col,
                                             const float* __restrict__ bias,
                                             const float* __restrict__ scale,
                                             float* __restrict__ out, int n) {
    int t = (blockIdx.x * 256 + threadIdx.x) >> 6;
    int lane = threadIdx.x & 63;
    if (t >= n) return;

    const char* Yb = (const char*)Y;
    uint_t lo4 = (uint_t)lane * 4;

    uint_t p = *(const uint_t*)(Yb + (((uint_t)t << 8) + lo4));
    float a0 = __uint_as_float(p << 16);
    float a1 = __uint_as_float(p & 0xFFFF0000u);

    int beg = rowptr[t];
    int end = rowptr[t + 1];
    for (int base = beg; base < end; base += 64) {
        int m = min(end - base, 64);
        uint_t cv = (uint_t)col[base + min(lane, m - 1)];   // 1 coalesced load = up to 64 indices
        int k = 0;
        for (; k + 16 <= m; k += 16) {
            uint_t qv[16];
#pragma unroll
            for (int j = 0; j < 16; ++j) {
                uint_t s = (uint_t)__builtin_amdgcn_readlane((int)cv, k + j);
                qv[j] = *(const uint_t*)(Yb + ((size_t)s << 8) + lo4);
            }
#pragma unroll
            for (int j = 0; j < 16; ++j) {
                a0 += __uint_as_float(qv[j] << 16);
                a1 += __uint_as_float(qv[j] & 0xFFFF0000u);
            }
        }
        for (; k + 4 <= m; k += 4) {
            uint_t qv[4];
#pragma unroll
            for (int j = 0; j < 4; ++j) {
                uint_t s = (uint_t)__builtin_amdgcn_readlane((int)cv, k + j);
                qv[j] = *(const uint_t*)(Yb + ((size_t)s << 8) + lo4);
            }
#pragma unroll
            for (int j = 0; j < 4; ++j) {
                a0 += __uint_as_float(qv[j] << 16);
                a1 += __uint_as_float(qv[j] & 0xFFFF0000u);
            }
        }
        for (; k < m; ++k) {
            uint_t s = (uint_t)__builtin_amdgcn_readlane((int)cv, k);
            uint_t q = *(const uint_t*)(Yb + ((size_t)s << 8) + lo4);
            a0 += __uint_as_float(q << 16);
            a1 += __uint_as_float(q & 0xFFFF0000u);
        }
    }

    float dt = dinv[t];
    float m0 = fmaf(dt, a0, bias[lane * 2]);
    float m1 = fmaf(dt, a1, bias[lane * 2 + 1]);

    float m2 = m0 * m0 + m1 * m1;
#pragma unroll
    for (int m = 32; m >= 1; m >>= 1) m2 += __shfl_xor(m2, m);

    float denom = fmaxf(sqrtf(m2), 1e-12f);
    float fac = xnorm[t] * scale[0] / denom;
    float g0 = m0 * fac;
    float g1 = m1 * fac;
    float2 o;
    o.x = 0.5f * g0 * (1.0f + erff(g0 * 0.70710678118654752440f));
    o.y = 0.5f * g1 * (1.0f + erff(g1 * 0.70710678118654752440f));
    *(float2*)&out[(size_t)t * D + lane * 2] = o;
}

// ---------------- launch ----------------

extern "C" void kernel_launch(void* const* d_in, const int* in_sizes, int n_in,
                              void* d_out, int out_size, void* d_ws, size_t ws_size,
                              hipStream_t stream) {
    const float* X     = (const float*)d_in[0];
    const int*   ei    = (const int*)d_in[1];
    const float* W     = (const float*)d_in[2];
    const float* bias  = (const float*)d_in[3];
    const float* scale = (const float*)d_in[4];
    float* out = (float*)d_out;

    int n = in_sizes[0] / D;     // 100000
    int e = in_sizes[1] / 2;     // 3200000
    const int* src = ei;
    const int* tgt = ei + e;

    char* ws = (char*)d_ws;
    ushort_t* Y = (ushort_t*)ws;   ws += (size_t)n * D * sizeof(ushort_t);   // 25.6 MB
    uint_t* binned = (uint_t*)Y;   // aliases Y (14.4 MB): dead before k_gemm writes Y
    float* dinv = (float*)ws;      ws += (size_t)n * sizeof(float);
    float* xnorm = (float*)ws;     ws += (size_t)n * sizeof(float);
    int* rowptr = (int*)ws;        ws += (size_t)(n + 1) * sizeof(int);
    int* bucket_cur = (int*)ws;    ws += NB * sizeof(int);
    int* col = (int*)ws;           ws += (size_t)e * sizeof(int);            // 12.8 MB
    ushort_t* Wt = (ushort_t*)ws;  /* 32 KB */

    hipMemsetAsync(bucket_cur, 0, NB * sizeof(int), stream);
    k_bin<<<(e + EPB - 1) / EPB, 1024, 0, stream>>>(src, tgt, e, bucket_cur, binned, W, Wt);
    k_sort<<<NB, 256, 0, stream>>>(binned, bucket_cur, col, rowptr, dinv, n);
    k_gemm<<<(n + 63) / 64, 256, 0, stream>>>(X, Wt, dinv, Y, xnorm, n);
    k_agg<<<(n + 3) / 4, 256, 0, stream>>>(Y, xnorm, dinv, rowptr, col, bias, scale, out, n);
}

// Round 8
// 305.892 us; speedup vs baseline: 1.3295x; 1.0251x over previous
//
#include <hip/hip_runtime.h>
#include <math.h>

#define D 128
#define NB 391         // buckets of 256 targets
#define BSH 8
#define BMASK 255
#define CAP 10240      // per-bucket capacity (mean 8184, +22 sigma)
#define EPB 4096
#define LDA 136        // LDS row stride (bf16 units): 2-way bank aliasing = free

typedef unsigned short ushort_t;
typedef unsigned int uint_t;
typedef __attribute__((ext_vector_type(8))) short bfrag;   // 8 bf16 = 4 VGPRs
typedef __attribute__((ext_vector_type(4))) float ffrag;   // 4 fp32 acc

__device__ inline ushort_t f2bf(float f) {
    uint_t u = __float_as_uint(f);
    uint_t r = (u + 0x7FFFu + ((u >> 16) & 1u)) >> 16;
    return (ushort_t)r;
}

// ---------------- binning with in-LDS counting sort -> COALESCED run flush ----------------
// r5 PMC showed the old per-edge scattered 4B stores caused ~10x write amplification
// (128 MB written for a 12.8 MB array; partial-line evictions). Sorting the block's
// edges by bucket in LDS first turns the flush into contiguous runs (avg 10.5 entries).
__global__ __launch_bounds__(256) void k_bin(const int* __restrict__ src,
                                             const int* __restrict__ tgt, int e,
                                             int* __restrict__ bucket_cur,
                                             uint_t* __restrict__ binned,
                                             const float* __restrict__ W,
                                             ushort_t* __restrict__ Wt) {
    __shared__ uint_t sval[EPB];      // 16 KB sorted packed edges
    __shared__ ushort_t sbkt[EPB];    // 8 KB bucket id per sorted entry
    __shared__ int lcnt[NB];          // histogram, then local cursor
    __shared__ int lbeg[NB];          // local exclusive offsets
    __shared__ int gbase[NB];         // global base per bucket
    __shared__ int pscan[256];
    int tid = threadIdx.x;

    // fused Wt[n][k] = bf16(W[k][n]) — 16 blocks x 1024 elems
    if (blockIdx.x < 16) {
        int nrow = blockIdx.x * 8 + (tid >> 5);
        int k0 = (tid & 31) * 4;
        ushort4 o;
        o.x = f2bf(W[(size_t)(k0 + 0) * D + nrow]);
        o.y = f2bf(W[(size_t)(k0 + 1) * D + nrow]);
        o.z = f2bf(W[(size_t)(k0 + 2) * D + nrow]);
        o.w = f2bf(W[(size_t)(k0 + 3) * D + nrow]);
        *(ushort4*)&Wt[(size_t)nrow * D + k0] = o;
    }

    int base = blockIdx.x * EPB;
    for (int i = tid; i < NB; i += 256) lcnt[i] = 0;
    __syncthreads();

    // pass 1: histogram
    int myb[16];
    uint_t myval[16];
#pragma unroll
    for (int k = 0; k < 16; ++k) {
        int i = base + k * 256 + tid;
        if (i < e) {
            int t = tgt[i];
            int s = src[i];
            myb[k] = t >> BSH;
            myval[k] = ((uint_t)s << BSH) | (uint_t)(t & BMASK);
            atomicAdd(&lcnt[myb[k]], 1);
        } else {
            myb[k] = -1;
        }
    }
    __syncthreads();

    // exclusive scan over NB counters (pair per thread, Hillis-Steele over pairs)
    int c0 = (2 * tid < NB) ? lcnt[2 * tid] : 0;
    int c1 = (2 * tid + 1 < NB) ? lcnt[2 * tid + 1] : 0;
    int x = c0 + c1;
    pscan[tid] = x;
    __syncthreads();
    for (int off = 1; off < 256; off <<= 1) {
        int y = (tid >= off) ? pscan[tid - off] : 0;
        __syncthreads();
        x += y;
        pscan[tid] = x;
        __syncthreads();
    }
    int pb = x - (c0 + c1);
    if (2 * tid < NB) lbeg[2 * tid] = pb;
    if (2 * tid + 1 < NB) lbeg[2 * tid + 1] = pb + c0;
    __syncthreads();

    // one global atomic per (block, bucket); reset lcnt as local scatter cursor
    for (int i = tid; i < NB; i += 256) {
        int c = lcnt[i];
        gbase[i] = (c > 0) ? atomicAdd(&bucket_cur[i], c) : 0;
        lcnt[i] = lbeg[i];
    }
    __syncthreads();

    // pass 2: rank-scatter into sorted LDS order
#pragma unroll
    for (int k = 0; k < 16; ++k) {
        if (myb[k] >= 0) {
            int r = atomicAdd(&lcnt[myb[k]], 1);
            sval[r] = myval[k];
            sbkt[r] = (ushort_t)myb[k];
        }
    }
    __syncthreads();

    // coalesced flush: sorted entry i -> contiguous slot in its bucket's slice
    int nb = min(e - base, EPB);
    for (int i = tid; i < nb; i += 256) {
        int b = sbkt[i];
        int slot = gbase[b] + (i - lbeg[b]);
        if (slot < CAP) binned[(size_t)b * CAP + slot] = sval[i];
    }
}

// ---------------- per-bucket LDS counting sort (+ fused bucket-base prefix) ----------------
__global__ __launch_bounds__(256) void k_sort(const uint_t* __restrict__ binned,
                                              const int* __restrict__ bucket_cur,
                                              int* __restrict__ col,
                                              int* __restrict__ rowptr,
                                              float* __restrict__ dinv, int n) {
    __shared__ uint_t sout[CAP];     // 40 KB
    __shared__ int scnt[256];
    __shared__ int sincl[256];
    __shared__ int sofs[256];
    __shared__ int sred[256];
    int b = blockIdx.x;
    int tid = threadIdx.x;

    // bucket base = sum of counts of buckets < b
    int v = 0;
    for (int i = tid; i < b; i += 256) v += min(bucket_cur[i], CAP);
    sred[tid] = v;
    __syncthreads();
    for (int off = 128; off >= 1; off >>= 1) {
        if (tid < off) sred[tid] += sred[tid + off];
        __syncthreads();
    }
    int baseg = sred[0];

    int nb = min(bucket_cur[b], CAP);
    const uint_t* bin = binned + (size_t)b * CAP;

    scnt[tid] = 0;
    __syncthreads();
    for (int i = tid; i < nb; i += 256)
        atomicAdd(&scnt[bin[i] & BMASK], 1);
    __syncthreads();
    int x = scnt[tid];
    sincl[tid] = x;
    __syncthreads();
    for (int off = 1; off < 256; off <<= 1) {
        int y = (tid >= off) ? sincl[tid - off] : 0;
        __syncthreads();
        x += y;
        sincl[tid] = x;
        __syncthreads();
    }
    sofs[tid] = x - scnt[tid];
    int t = (b << BSH) + tid;
    if (t < n) {
        rowptr[t + 1] = baseg + x;
        dinv[t] = rsqrtf((float)scnt[tid] + 1.0f);
    }
    if (b == 0 && tid == 0) rowptr[0] = 0;
    __syncthreads();
    for (int i = tid; i < nb; i += 256) {
        uint_t w = bin[i];
        int r = atomicAdd(&sofs[w & BMASK], 1);
        sout[r] = w >> BSH;
    }
    __syncthreads();
    for (int i = tid; i < nb; i += 256)
        col[baseg + i] = (int)sout[i];
}

// ---------------- Y = dinv*(X@W) bf16 via MFMA (transposed-operand trick), xnorm fused ----------------
// Epilogue routes the output tile through LDS (reusing As, same LDA) so global Y stores
// are full 64-B lines (old path: 64 scattered 8-B stores per wave-instruction).
__global__ __launch_bounds__(256) void k_gemm(const float* __restrict__ X,
                                              const ushort_t* __restrict__ Wt,
                                              const float* __restrict__ dinv,
                                              ushort_t* __restrict__ Y,
                                              float* __restrict__ xnorm, int n) {
    __shared__ ushort_t As[64 * LDA];    // X tile, bf16 (reused as output tile)
    __shared__ ushort_t Bs[128 * LDA];   // Wt (n x k), bf16
    int tid = threadIdx.x;
    int row0 = blockIdx.x * 64;

    for (int i = tid; i < 128 * 16; i += 256) {
        int nr = i >> 4, c = (i & 15) << 3;
        *(uint4*)&Bs[nr * LDA + c] = *(const uint4*)&Wt[(size_t)nr * D + c];
    }

    const float4* X4 = (const float4*)X;
#pragma unroll
    for (int i2 = 0; i2 < 8; ++i2) {
        int item = i2 * 256 + tid;
        int r = item >> 5, c4 = item & 31;
        int gr = row0 + r;
        float4 v = (gr < n) ? X4[(size_t)gr * 32 + c4] : make_float4(0.f, 0.f, 0.f, 0.f);
        ushort4 bv;
        bv.x = f2bf(v.x); bv.y = f2bf(v.y); bv.z = f2bf(v.z); bv.w = f2bf(v.w);
        *(ushort4*)&As[r * LDA + c4 * 4] = bv;
        float s = v.x * v.x + v.y * v.y + v.z * v.z + v.w * v.w;
        s += __shfl_xor(s, 1);
        s += __shfl_xor(s, 2);
        s += __shfl_xor(s, 4);
        s += __shfl_xor(s, 8);
        s += __shfl_xor(s, 16);
        if ((tid & 31) == 0 && gr < n) xnorm[gr] = sqrtf(s);
    }
    __syncthreads();

    int w = tid >> 6;
    int lane = tid & 63;
    int q = lane >> 4;
    int mi = lane & 15;

    bfrag xf[4];
#pragma unroll
    for (int kt = 0; kt < 4; ++kt)
        xf[kt] = *(const bfrag*)&As[(w * 16 + mi) * LDA + kt * 32 + q * 8];

    ffrag acc[8];
#pragma unroll
    for (int nt = 0; nt < 8; ++nt) acc[nt] = (ffrag){0.f, 0.f, 0.f, 0.f};

#pragma unroll
    for (int nt = 0; nt < 8; ++nt) {
#pragma unroll
        for (int kt = 0; kt < 4; ++kt) {
            bfrag wf = *(const bfrag*)&Bs[(nt * 16 + mi) * LDA + kt * 32 + q * 8];
            acc[nt] = __builtin_amdgcn_mfma_f32_16x16x32_bf16(wf, xf[kt], acc[nt], 0, 0, 0);
        }
    }

    __syncthreads();   // all As/Bs reads done -> safe to reuse As as output tile
    int gr = row0 + w * 16 + mi;
    float dv = (gr < n) ? dinv[gr] : 0.f;
#pragma unroll
    for (int nt = 0; nt < 8; ++nt) {
        ushort4 o;
        o.x = f2bf(acc[nt][0] * dv);
        o.y = f2bf(acc[nt][1] * dv);
        o.z = f2bf(acc[nt][2] * dv);
        o.w = f2bf(acc[nt][3] * dv);
        *(ushort4*)&As[(w * 16 + mi) * LDA + nt * 16 + q * 4] = o;
    }
    __syncthreads();

    // coalesced copy-out: thread owns one 64-B line of Y
    int row = tid >> 2, seg = tid & 3;
    int grow = row0 + row;
    if (grow < n) {
#pragma unroll
        for (int k2 = 0; k2 < 4; ++k2) {
            uint4 vv = *(const uint4*)&As[row * LDA + seg * 32 + k2 * 8];
            *(uint4*)&Y[(size_t)grow * D + seg * 32 + k2 * 8] = vv;
        }
    }
}

// ---------------- fused aggregation + MessageNorm + GELU (wave per target) ----------------
__global__ __launch_bounds__(256) void k_agg(const ushort_t* __restrict__ Y,
                                             const float* __restrict__ xnorm,
                                             const float* __restrict__ dinv,
                                             const int* __restrict__ rowptr,
                                             const int* __restrict__ col,
                                             const float* __restrict__ bias,
                                             const float* __restrict__ scale,
                                             float* __restrict__ out, int n) {
    int t = (blockIdx.x * 256 + threadIdx.x) >> 6;
    int lane = threadIdx.x & 63;
    if (t >= n) return;

    const char* Yb = (const char*)Y;
    uint_t lo4 = (uint_t)lane * 4;

    uint_t p = *(const uint_t*)(Yb + (((uint_t)t << 8) + lo4));
    float a0 = __uint_as_float(p << 16);
    float a1 = __uint_as_float(p & 0xFFFF0000u);

    int beg = rowptr[t];
    int end = rowptr[t + 1];
    for (int base = beg; base < end; base += 64) {
        int m = min(end - base, 64);
        uint_t cv = (uint_t)col[base + min(lane, m - 1)];   // 1 coalesced load = up to 64 indices
        int k = 0;
        for (; k + 16 <= m; k += 16) {
            uint_t qv[16];
#pragma unroll
            for (int j = 0; j < 16; ++j) {
                uint_t s = (uint_t)__builtin_amdgcn_readlane((int)cv, k + j);
                qv[j] = *(const uint_t*)(Yb + ((size_t)s << 8) + lo4);
            }
#pragma unroll
            for (int j = 0; j < 16; ++j) {
                a0 += __uint_as_float(qv[j] << 16);
                a1 += __uint_as_float(qv[j] & 0xFFFF0000u);
            }
        }
        for (; k + 4 <= m; k += 4) {
            uint_t qv[4];
#pragma unroll
            for (int j = 0; j < 4; ++j) {
                uint_t s = (uint_t)__builtin_amdgcn_readlane((int)cv, k + j);
                qv[j] = *(const uint_t*)(Yb + ((size_t)s << 8) + lo4);
            }
#pragma unroll
            for (int j = 0; j < 4; ++j) {
                a0 += __uint_as_float(qv[j] << 16);
                a1 += __uint_as_float(qv[j] & 0xFFFF0000u);
            }
        }
        for (; k < m; ++k) {
            uint_t s = (uint_t)__builtin_amdgcn_readlane((int)cv, k);
            uint_t q = *(const uint_t*)(Yb + ((size_t)s << 8) + lo4);
            a0 += __uint_as_float(q << 16);
            a1 += __uint_as_float(q & 0xFFFF0000u);
        }
    }

    float dt = dinv[t];
    float m0 = fmaf(dt, a0, bias[lane * 2]);
    float m1 = fmaf(dt, a1, bias[lane * 2 + 1]);

    float m2 = m0 * m0 + m1 * m1;
#pragma unroll
    for (int m = 32; m >= 1; m >>= 1) m2 += __shfl_xor(m2, m);

    float denom = fmaxf(sqrtf(m2), 1e-12f);
    float fac = xnorm[t] * scale[0] / denom;
    float g0 = m0 * fac;
    float g1 = m1 * fac;
    float2 o;
    o.x = 0.5f * g0 * (1.0f + erff(g0 * 0.70710678118654752440f));
    o.y = 0.5f * g1 * (1.0f + erff(g1 * 0.70710678118654752440f));
    *(float2*)&out[(size_t)t * D + lane * 2] = o;
}

// ---------------- launch ----------------

extern "C" void kernel_launch(void* const* d_in, const int* in_sizes, int n_in,
                              void* d_out, int out_size, void* d_ws, size_t ws_size,
                              hipStream_t stream) {
    const float* X     = (const float*)d_in[0];
    const int*   ei    = (const int*)d_in[1];
    const float* W     = (const float*)d_in[2];
    const float* bias  = (const float*)d_in[3];
    const float* scale = (const float*)d_in[4];
    float* out = (float*)d_out;

    int n = in_sizes[0] / D;     // 100000
    int e = in_sizes[1] / 2;     // 3200000
    const int* src = ei;
    const int* tgt = ei + e;

    char* ws = (char*)d_ws;
    ushort_t* Y = (ushort_t*)ws;   ws += (size_t)n * D * sizeof(ushort_t);   // 25.6 MB
    uint_t* binned = (uint_t*)Y;   // aliases Y (16.0 MB): dead before k_gemm writes Y
    float* dinv = (float*)ws;      ws += (size_t)n * sizeof(float);
    float* xnorm = (float*)ws;     ws += (size_t)n * sizeof(float);
    int* rowptr = (int*)ws;        ws += (size_t)(n + 1) * sizeof(int);
    int* bucket_cur = (int*)ws;    ws += NB * sizeof(int);
    int* col = (int*)ws;           ws += (size_t)e * sizeof(int);            // 12.8 MB
    ushort_t* Wt = (ushort_t*)ws;  /* 32 KB */

    hipMemsetAsync(bucket_cur, 0, NB * sizeof(int), stream);
    k_bin<<<(e + EPB - 1) / EPB, 256, 0, stream>>>(src, tgt, e, bucket_cur, binned, W, Wt);
    k_sort<<<NB, 256, 0, stream>>>(binned, bucket_cur, col, rowptr, dinv, n);
    k_gemm<<<(n + 63) / 64, 256, 0, stream>>>(X, Wt, dinv, Y, xnorm, n);
    k_agg<<<(n + 3) / 4, 256, 0, stream>>>(Y, xnorm, dinv, rowptr, col, bias, scale, out, n);
}